// Round 5
// baseline (434.038 us; speedup 1.0000x reference)
//
#include <hip/hip_runtime.h>

// MS-Deformable Attention, MI355X gfx950.
// Pipeline: prep(weights->bf16,[N][K]) ; v=value@Wv (bf16 MFMA, out bf16)
//           p=query@[Woff|Wattn] (bf16 MFMA, out fp32, N padded to 128)
//           sampling (bilinear gather from bf16 v, out bf16)
//           out = samp@Wo + b + query (bf16 MFMA, fp32 out)
// R6: sample_k sched_barrier pin (61->54us). GEMM no-vmcnt-drain pipeline:
//     neutral -- occupancy pinned at 1 block/CU (104KB LDS, 2 waves/SIMD).
// R7: GEMM occupancy attack: BK=32 (8 chunks), LDS pitch 34 (17-bank stride,
//     max 2-way conflict = free) -> A+B double-buffered in 52KB -> 2 blocks/CU
//     = 4 waves/SIMD. VGPR re-budgeted ~116 <= 128 (launch_bounds(512,4)).
//     Pipeline: load(c+2) || compute(c) || store(c+1), one lgkm-only barrier
//     per chunk; global loads stay in flight across barriers (vmcnt is an
//     in-order counter -> B must stay in LDS, staged with A).

typedef float  f4  __attribute__((ext_vector_type(4)));
typedef float  fx4 __attribute__((ext_vector_type(4)));
typedef short  s8  __attribute__((ext_vector_type(8)));
typedef short  s4  __attribute__((ext_vector_type(4)));
typedef int    i4  __attribute__((ext_vector_type(4)));
typedef unsigned int u4 __attribute__((ext_vector_type(4)));

#define KDIM    256
#define NVPIX   40000
#define GH      200
#define GW      200
#define LDP     34          // LDS row pitch in shorts: 32 data + 2 pad
                            // stride = 68B = 17 banks (odd) -> max 2-way (free)

__device__ __forceinline__ short f2bf(float f) {
  union { float f; unsigned u; } v; v.f = f;
  unsigned r = v.u + 0x7fffu + ((v.u >> 16) & 1u);   // round-to-nearest-even
  return (short)(r >> 16);
}
__device__ __forceinline__ float bf2f(unsigned short h) {
  union { unsigned u; float f; } v; v.u = ((unsigned)h) << 16; return v.f;
}
__device__ __forceinline__ float asf(unsigned u) {
  union { unsigned u; float f; } v; v.u = u; return v.f;
}

// ---------------------------------------------------------------- prep ----
__global__ void prep_k(const float* __restrict__ Wv, const float* __restrict__ Wo,
                       const float* __restrict__ Woff, const float* __restrict__ Wattn,
                       const float* __restrict__ boff, const float* __restrict__ battn,
                       unsigned short* __restrict__ Wv_t, unsigned short* __restrict__ Wo_t,
                       unsigned short* __restrict__ Wp_t, float* __restrict__ bp)
{
  int i = blockIdx.x * 256 + threadIdx.x;
  if (i < 65536) {
    int n = i >> 8, k = i & 255;
    Wv_t[i] = (unsigned short)f2bf(Wv[k * 256 + n]);
  } else if (i < 131072) {
    int j = i - 65536; int n = j >> 8, k = j & 255;
    Wo_t[j] = (unsigned short)f2bf(Wo[k * 256 + n]);
  } else if (i < 163840) {
    int j = i - 131072; int n = j >> 8, k = j & 255;
    float val = (n < 64) ? Woff[k * 64 + n] : ((n < 96) ? Wattn[k * 32 + (n - 64)] : 0.f);
    Wp_t[j] = (unsigned short)f2bf(val);
  } else if (i < 163968) {
    int j = i - 163840;
    bp[j] = (j < 64) ? boff[j] : ((j < 96) ? battn[j - 64] : 0.f);
  }
}

// ---------------------------------------------------------------- GEMM ----
// C[M,BN] = A[M,K=256] * B^T (Bt [BN][K] bf16) + bias (+resid). 128xBN tile,
// BK=32 (8 chunks), 8 waves (grid 2x4, per-wave 64x(BN/4)), one MFMA-K per
// chunk. Double-buffered LDS (A and B), 2 register prefetch sets.
// Schedule (chunk n lives in set n&1 and buf n&1):
//   pro: load(0,s0); load(1,s1); store(b0,s0); BAR;
//   c=0..6: [load(c+2, s_{c&1})]; compute(b_{c&1}); store(b_{(c+1)&1}, s_{(c+1)&1}); BAR;
//   compute(b1);
// BAR = lgkmcnt(0)+s_barrier only: chunk c+2's global loads stay in flight
// across the barrier, consumed by store one full iter later.
template<int ABF, int CBF, int RES, int BN>
__global__ __launch_bounds__(512, 4)
void gemm_k(const void* __restrict__ Ap, const unsigned short* __restrict__ Bt,
            const float* __restrict__ bias, const float* __restrict__ resid,
            void* __restrict__ Cp)
{
  constexpr int ACCJ = BN / 64;        // 4 (BN=256) or 2 (BN=128)
  constexpr int WN   = BN / 4;         // per-wave N extent: 64 or 32
  constexpr int BS8  = BN / 128;       // B s8 loads per thread per chunk
  __shared__ short As[2][128 * LDP];   // 2*128*34*2  = 17408 B
  __shared__ short Bs[2][BN  * LDP];   // 2*BN*34*2   = 34816 B (BN=256)
  const int t  = threadIdx.x;
  const int m0 = blockIdx.x * 128;
  const int lane = t & 63;
  const int w  = t >> 6;               // 0..7
  const int wm = (w >> 2) * 64;        // 0,64
  const int wn = (w & 3) * WN;
  const int fr = lane & 15;
  const int quad = lane >> 4;

  fx4 acc[4][ACCJ];
  #pragma unroll
  for (int i = 0; i < 4; i++)
    #pragma unroll
    for (int j = 0; j < ACCJ; j++) { fx4 z = {0.f, 0.f, 0.f, 0.f}; acc[i][j] = z; }

  f4 paf[2][2];    // ABF=0: 128x32 f32 chunk = 1024 f4 -> 2/thread, 2 sets
  s8 pab[2];       // ABF=1: 128x32 bf16 chunk = 512 s8 -> 1/thread, 2 sets
  s8 pbv[2][BS8];  // B: BNx32 bf16 chunk -> BS8/thread, 2 sets

  auto loadAB = [&](int k0, int s) {
    if (ABF) {
      const unsigned short* base = (const unsigned short*)Ap + (size_t)m0 * KDIM + k0;
      pab[s] = *(const s8*)(base + (size_t)(t >> 2) * KDIM + (t & 3) * 8);
    } else {
      const float* base = (const float*)Ap + (size_t)m0 * KDIM + k0;
      #pragma unroll
      for (int j = 0; j < 2; j++) {
        int id = t + j * 512;                   // 8 f4 per row, coalesced
        paf[s][j] = *(const f4*)(base + (size_t)(id >> 3) * KDIM + (id & 7) * 4);
      }
    }
    const unsigned short* bbase = Bt + k0;
    #pragma unroll
    for (int j = 0; j < BS8; j++) {
      int id = t + j * 512;                     // 4 s8 per row
      pbv[s][j] = *(const s8*)(bbase + (size_t)(id >> 2) * KDIM + (id & 3) * 8);
    }
  };
  auto storeAB = [&](int buf, int s) {
    if (ABF) {
      *(s8*)(&As[buf][(t >> 2) * LDP + (t & 3) * 8]) = pab[s];
    } else {
      #pragma unroll
      for (int j = 0; j < 2; j++) {
        int id = t + j * 512;
        s4 c;
        #pragma unroll
        for (int e = 0; e < 4; e++) c[e] = f2bf(paf[s][j][e]);
        *(s4*)(&As[buf][(id >> 3) * LDP + (id & 7) * 4]) = c;   // ds_write_b64
      }
    }
    #pragma unroll
    for (int j = 0; j < BS8; j++) {
      int id = t + j * 512;
      *(s8*)(&Bs[buf][(id >> 2) * LDP + (id & 3) * 8]) = pbv[s][j];  // ds_write_b128
    }
  };
  auto compute = [&](int buf) {
    s8 bfr[ACCJ];
    #pragma unroll
    for (int j = 0; j < ACCJ; j++)
      bfr[j] = *(const s8*)(&Bs[buf][(wn + j * 16 + fr) * LDP + quad * 8]);
    #pragma unroll
    for (int i = 0; i < 4; i++) {
      s8 afr = *(const s8*)(&As[buf][(wm + i * 16 + fr) * LDP + quad * 8]);
      #pragma unroll
      for (int j = 0; j < ACCJ; j++)
        acc[i][j] = __builtin_amdgcn_mfma_f32_16x16x32_bf16(afr, bfr[j], acc[i][j], 0, 0, 0);
    }
  };

  // BAR: drain LDS ops only; global loads remain in flight across barrier.
#define GBAR() do { asm volatile("s_waitcnt lgkmcnt(0)" ::: "memory"); \
                    __builtin_amdgcn_s_barrier(); } while (0)

  loadAB(0, 0);
  loadAB(32, 1);
  storeAB(0, 0);           // waits chunk0 loads only (chunk1 still flying)
  GBAR();
  #pragma unroll
  for (int c = 0; c < 7; ++c) {
    if (c < 6) loadAB((c + 2) * 32, c & 1);    // chunk c+2 in flight across BAR
    compute(c & 1);                            // chunk c
    storeAB((c + 1) & 1, (c + 1) & 1);         // chunk c+1 (loaded last iter)
    GBAR();
  }
  compute(1);              // chunk 7
#undef GBAR

  // Epilogue: C/D layout col=lane&15, row=quad*4+reg (verified m89/m91).
  #pragma unroll
  for (int i = 0; i < 4; i++) {
    const int mbase = m0 + wm + i * 16 + quad * 4;
    #pragma unroll
    for (int j = 0; j < ACCJ; j++) {
      const int n = wn + j * 16 + fr;
      const float bn = bias[n];
      #pragma unroll
      for (int r = 0; r < 4; r++) {
        const size_t m = (size_t)(mbase + r);
        float v = acc[i][j][r] + bn;
        if (RES) v += resid[m * (size_t)BN + n];
        if (CBF) ((unsigned short*)Cp)[m * (size_t)BN + n] = (unsigned short)f2bf(v);
        else     ((float*)Cp)[m * (size_t)BN + n] = v;
      }
    }
  }
}

// ------------------------------------------------------------- sampling ----
// 8 queries per block, 256 threads. Phase A: one (qi,h,pt) per thread ->
// weights/offsets in LDS. Phase B: one (qi,h,dg) per thread; 16 gathers
// issued then sched_barrier(0) pin; dword-pair bf16 unpack FMA.
__global__ __launch_bounds__(256, 4)
void sample_k(const unsigned short* __restrict__ v, const float* __restrict__ p,
              const float* __restrict__ ref, unsigned short* __restrict__ o)
{
  const int t  = threadIdx.x;
  const int q0 = blockIdx.x * 8;
  __shared__ float sp[8][128];
  __shared__ float sref[16];
  __shared__ float sw[8][8][4][4];   // [qi][h][pt][corner] weights
  __shared__ int   so[8][8][4][4];   // [qi][h][pt][corner] element offsets
  {
    const float* pb = p + (size_t)q0 * 128;
    float* spf = &sp[0][0];
    *(f4*)(spf + t * 4) = *(const f4*)(pb + t * 4);
    if (t < 16) sref[t] = ref[(size_t)q0 * 2 + t];
  }
  __syncthreads();

  // ---- Phase A: one (qi,h,pt) per thread ----
  {
    const int qa = t >> 5;
    const int ha = (t >> 2) & 7;
    const int pa_ = t & 3;
    const float lg0 = sp[qa][64 + ha * 4 + 0], lg1 = sp[qa][64 + ha * 4 + 1];
    const float lg2 = sp[qa][64 + ha * 4 + 2], lg3 = sp[qa][64 + ha * 4 + 3];
    const float mx = fmaxf(fmaxf(lg0, lg1), fmaxf(lg2, lg3));
    const float e0 = __expf(lg0 - mx), e1 = __expf(lg1 - mx);
    const float e2 = __expf(lg2 - mx), e3 = __expf(lg3 - mx);
    const float inv = 1.f / (e0 + e1 + e2 + e3);
    const float a = ((pa_ == 0) ? e0 : (pa_ == 1) ? e1 : (pa_ == 2) ? e2 : e3) * inv;
    const float rx = sref[qa * 2], ry = sref[qa * 2 + 1];
    const float ox = sp[qa][ha * 8 + pa_ * 2], oy = sp[qa][ha * 8 + pa_ * 2 + 1];
    // px = loc_x*W - 0.5 with loc_x = rx + ox/W  ->  rx*W + ox - 0.5
    const float px = rx * 200.f + ox - 0.5f;
    const float py = ry * 200.f + oy - 0.5f;
    const float x0f = floorf(px), y0f = floorf(py);
    const int ix = (int)x0f, iy = (int)y0f;
    const float fx = px - x0f, fy = py - y0f;
    const float vx0 = (ix >= 0 && ix < GW) ? 1.f : 0.f;
    const float vx1 = (ix + 1 >= 0 && ix + 1 < GW) ? 1.f : 0.f;
    const float vy0 = (iy >= 0 && iy < GH) ? 1.f : 0.f;
    const float vy1 = (iy + 1 >= 0 && iy + 1 < GH) ? 1.f : 0.f;
    f4 wv;
    wv[0] = a * (1.f - fx) * (1.f - fy) * vx0 * vy0;
    wv[1] = a * fx * (1.f - fy) * vx1 * vy0;
    wv[2] = a * (1.f - fx) * fy * vx0 * vy1;
    wv[3] = a * fx * fy * vx1 * vy1;
    const int ix0c = min(max(ix, 0), GW - 1);
    const int ix1c = min(max(ix + 1, 0), GW - 1);
    const int iy0c = min(max(iy, 0), GH - 1);
    const int iy1c = min(max(iy + 1, 0), GH - 1);
    const int r0 = iy0c * (GW * 256);
    const int r1 = iy1c * (GW * 256);
    i4 ov;
    ov[0] = r0 + ix0c * 256;
    ov[1] = r0 + ix1c * 256;
    ov[2] = r1 + ix0c * 256;
    ov[3] = r1 + ix1c * 256;
    *(f4*)&sw[qa][ha][pa_][0] = wv;
    *(i4*)&so[qa][ha][pa_][0] = ov;
  }
  __syncthreads();

  // ---- Phase B: one (qi,h,dg) per thread; gathers pinned in flight ----
  const int qi = t >> 5;
  const int h  = (t >> 2) & 7;
  const int dg = t & 3;
  const int q  = q0 + qi;
  // q0 multiple of 8 -> whole block same batch
  const unsigned short* vb = v + ((q0 >= 40000) ? (size_t)NVPIX * 256 : 0);
  const int cbase = h * 32 + dg * 8;

  i4 ofs[4];
  #pragma unroll
  for (int pt = 0; pt < 4; pt++) ofs[pt] = *(const i4*)&so[qi][h][pt][0];

  u4 g[16];
  #pragma unroll
  for (int pt = 0; pt < 4; pt++)
    #pragma unroll
    for (int c = 0; c < 4; c++)
      g[pt * 4 + c] = *(const u4*)(vb + (unsigned)(ofs[pt][c] + cbase));

  // Pin: nothing below may be scheduled above this point.
  __builtin_amdgcn_sched_barrier(0);

  f4 wts[4];
  #pragma unroll
  for (int pt = 0; pt < 4; pt++) wts[pt] = *(const f4*)&sw[qi][h][pt][0];

  float acc[8];
  #pragma unroll
  for (int e = 0; e < 8; e++) acc[e] = 0.f;

  #pragma unroll
  for (int pt = 0; pt < 4; pt++) {
    #pragma unroll
    for (int c = 0; c < 4; c++) {
      const float wk = wts[pt][c];
      const u4 gu = g[pt * 4 + c];
      #pragma unroll
      for (int d = 0; d < 4; d++) {
        const unsigned u = gu[d];
        acc[2 * d]     += wk * asf(u << 16);           // low bf16
        acc[2 * d + 1] += wk * asf(u & 0xffff0000u);   // high bf16
      }
    }
  }

  s8 res;
  #pragma unroll
  for (int e = 0; e < 8; e++) res[e] = f2bf(acc[e]);
  *(s8*)(o + (size_t)q * 256 + cbase) = res;
}

// --------------------------------------------------------------- launch ----
extern "C" void kernel_launch(void* const* d_in, const int* in_sizes, int n_in,
                              void* d_out, int out_size, void* d_ws, size_t ws_size,
                              hipStream_t stream)
{
  const float* query = (const float*)d_in[0];
  const float* value = (const float*)d_in[1];
  const float* refp  = (const float*)d_in[2];
  // d_in[3] spatial_shapes: compile-time (200,200)
  const float* Wv    = (const float*)d_in[4];
  const float* bv    = (const float*)d_in[5];
  const float* Woff  = (const float*)d_in[6];
  const float* boff  = (const float*)d_in[7];
  const float* Wattn = (const float*)d_in[8];
  const float* battn = (const float*)d_in[9];
  const float* Wo    = (const float*)d_in[10];
  const float* bo    = (const float*)d_in[11];

  char* ws = (char*)d_ws;
  unsigned short* ws_v = (unsigned short*)ws;                  // 80000*256 bf16 = 40.96 MB
  float*          ws_p = (float*)(ws + 40960000);              // 80000*128 f32  = 40.96 MB
  unsigned short* ws_o = (unsigned short*)(ws + 81920000);     // 80000*256 bf16 = 40.96 MB
  unsigned short* Wv_t = (unsigned short*)(ws + 122880000);    // 256*256 bf16
  unsigned short* Wo_t = Wv_t + 65536;                         // 256*256 bf16
  unsigned short* Wp_t = Wo_t + 65536;                         // 128*256 bf16
  float*          bp   = (float*)(Wp_t + 32768);               // 128 f32

  hipLaunchKernelGGL(prep_k, dim3(641), dim3(256), 0, stream,
                     Wv, Wo, Woff, Wattn, boff, battn, Wv_t, Wo_t, Wp_t, bp);
  // v = value @ Wv + bv  -> bf16   (A read once: 128x256 tile per block)
  hipLaunchKernelGGL((gemm_k<0, 1, 0, 256>), dim3(625), dim3(512), 0, stream,
                     (const void*)value, Wv_t, bv, (const float*)nullptr, (void*)ws_v);
  // p = query @ [Woff|Wattn|0] + bp -> f32 (stride 128)
  hipLaunchKernelGGL((gemm_k<0, 0, 0, 128>), dim3(625), dim3(512), 0, stream,
                     (const void*)query, Wp_t, bp, (const float*)nullptr, (void*)ws_p);
  // sampling
  hipLaunchKernelGGL(sample_k, dim3(10000), dim3(256), 0, stream,
                     ws_v, ws_p, refp, ws_o);
  // out = samp @ Wo + bo + query -> f32
  hipLaunchKernelGGL((gemm_k<1, 0, 1, 256>), dim3(625), dim3(512), 0, stream,
                     (const void*)ws_o, Wo_t, bo, query, (void*)d_out);
}

// Round 8
// 424.994 us; speedup vs baseline: 1.0213x; 1.0213x over previous
//
#include <hip/hip_runtime.h>

// MS-Deformable Attention, MI355X gfx950.
// Pipeline: prep(weights->bf16,[N][K]) ; fused{v=value@Wv, p=query@Wp} ;
//           sampling (bilinear gather) ; out = samp@Wo + b + query.
// R7 post-mortem: __launch_bounds__(512,4) -> VGPR 64 -> acc-only, massive
//   spill (WRITE 132MB, 106us/gemm). 2nd launch_bounds arg costs ~2x the
//   documented formula on this toolchain (R4: (256,8)->32 VGPR, R7:
//   (512,4)->64). NEVER cap regs below the 64-VGPR accumulator.
// R8: (a) GEMM reverted to the R0-proven body (256 thr, 128x128 tile, BK=64,
//         reg-prefetch, plain __syncthreads, no min-wave arg).
//     (b) v-gemm and p-gemm are independent -> fused into ONE dispatch
//         (grid 625x3: y<2 -> v quadrants, y=2 -> p). 1875 blocks of
//         independent HBM streams fill each other's latency bubbles and one
//         launch gap disappears.
// R9: fix compile error (missing (float*) cast on d_out).
// R10: resubmit of R9 — container-acquire infra failure, kernel never ran.

typedef float  f4  __attribute__((ext_vector_type(4)));
typedef float  fx4 __attribute__((ext_vector_type(4)));
typedef short  s8  __attribute__((ext_vector_type(8)));
typedef short  s4  __attribute__((ext_vector_type(4)));
typedef int    i4  __attribute__((ext_vector_type(4)));
typedef unsigned int u4 __attribute__((ext_vector_type(4)));

#define KDIM    256
#define NVPIX   40000
#define GH      200
#define GW      200
#define LDP     68          // LDS row pitch in shorts: 64 data + 4 pad -> conflict-free

__device__ __forceinline__ short f2bf(float f) {
  union { float f; unsigned u; } v; v.f = f;
  unsigned r = v.u + 0x7fffu + ((v.u >> 16) & 1u);   // round-to-nearest-even
  return (short)(r >> 16);
}
__device__ __forceinline__ float bf2f(unsigned short h) {
  union { unsigned u; float f; } v; v.u = ((unsigned)h) << 16; return v.f;
}
__device__ __forceinline__ float asf(unsigned u) {
  union { unsigned u; float f; } v; v.u = u; return v.f;
}

// ---------------------------------------------------------------- prep ----
__global__ void prep_k(const float* __restrict__ Wv, const float* __restrict__ Wo,
                       const float* __restrict__ Woff, const float* __restrict__ Wattn,
                       const float* __restrict__ boff, const float* __restrict__ battn,
                       unsigned short* __restrict__ Wv_t, unsigned short* __restrict__ Wo_t,
                       unsigned short* __restrict__ Wp_t, float* __restrict__ bp)
{
  int i = blockIdx.x * 256 + threadIdx.x;
  if (i < 65536) {
    int n = i >> 8, k = i & 255;
    Wv_t[i] = (unsigned short)f2bf(Wv[k * 256 + n]);
  } else if (i < 131072) {
    int j = i - 65536; int n = j >> 8, k = j & 255;
    Wo_t[j] = (unsigned short)f2bf(Wo[k * 256 + n]);
  } else if (i < 163840) {
    int j = i - 131072; int n = j >> 8, k = j & 255;
    float val = (n < 64) ? Woff[k * 64 + n] : ((n < 96) ? Wattn[k * 32 + (n - 64)] : 0.f);
    Wp_t[j] = (unsigned short)f2bf(val);
  } else if (i < 163968) {
    int j = i - 163840;
    bp[j] = (j < 64) ? boff[j] : ((j < 96) ? battn[j - 64] : 0.f);
  }
}

// ----------------------------------------------------------- GEMM body ----
// C[m0:m0+128, n0:n0+128] = A[M,K=256] * B^T (Bt [N][K] bf16) + bias
// (+resid). 256 threads, 4 waves (2x2), per-wave 64x64 (acc[4][4]), BK=64
// (4 k-iters), register-prefetch pipeline (R0-proven: ~60us/gemm, no spill).
template<int ABF, int CBF, int RES>
__device__ __forceinline__
void gemm_body(const void* __restrict__ Ap, const unsigned short* __restrict__ Bt,
               const float* __restrict__ bias, const float* __restrict__ resid,
               void* __restrict__ Cp, int N, int m0, int n0,
               short* __restrict__ As, short* __restrict__ Bs)
{
  const int t  = threadIdx.x;
  const int lane = t & 63;
  const int w  = t >> 6;
  const int wm = (w >> 1) * 64;
  const int wn = (w & 1) * 64;
  const int fr = lane & 15;
  const int quad = lane >> 4;

  fx4 acc[4][4];
  #pragma unroll
  for (int i = 0; i < 4; i++)
    #pragma unroll
    for (int j = 0; j < 4; j++) { fx4 z = {0.f, 0.f, 0.f, 0.f}; acc[i][j] = z; }

  f4 pa[8];    // ABF=0 prefetch: 128x64 f32 tile = 2048 f4, 8 per thread
  s8 pa8[4];   // ABF=1 prefetch: 128x64 bf16 tile = 1024 s8, 4 per thread
  s8 pb[4];    // B prefetch

  auto loadA = [&](int k0) {
    if (ABF) {
      const unsigned short* base = (const unsigned short*)Ap + (size_t)m0 * KDIM + k0;
      #pragma unroll
      for (int j = 0; j < 4; j++) {
        int id = t + j * 256;                   // coalesced
        int row = id >> 3, kp = (id & 7) * 8;
        pa8[j] = *(const s8*)(base + (size_t)row * KDIM + kp);
      }
    } else {
      const float* base = (const float*)Ap + (size_t)m0 * KDIM + k0;
      #pragma unroll
      for (int j = 0; j < 8; j++) {
        int id = t + j * 256;                   // coalesced
        int row = id >> 4, kp = (id & 15) * 4;
        pa[j] = *(const f4*)(base + (size_t)row * KDIM + kp);
      }
    }
  };
  auto loadB = [&](int k0) {
    const unsigned short* base = Bt + (size_t)n0 * KDIM + k0;
    #pragma unroll
    for (int j = 0; j < 4; j++) {
      int id = t + j * 256;
      int row = id >> 3, kp = (id & 7) * 8;
      pb[j] = *(const s8*)(base + (size_t)row * KDIM + kp);
    }
  };
  auto storeAB = [&]() {
    if (ABF) {
      #pragma unroll
      for (int j = 0; j < 4; j++) {
        int id = t + j * 256;
        int row = id >> 3, kp = (id & 7) * 8;
        *(s8*)(&As[row * LDP + kp]) = pa8[j];
      }
    } else {
      #pragma unroll
      for (int j = 0; j < 8; j++) {
        int id = t + j * 256;
        int row = id >> 4, kp = (id & 15) * 4;
        s4 c;
        #pragma unroll
        for (int e = 0; e < 4; e++) c[e] = f2bf(pa[j][e]);
        *(s4*)(&As[row * LDP + kp]) = c;        // ds_write_b64, conflict-free
      }
    }
    #pragma unroll
    for (int j = 0; j < 4; j++) {
      int id = t + j * 256;
      int row = id >> 3, kp = (id & 7) * 8;
      *(s8*)(&Bs[row * LDP + kp]) = pb[j];      // ds_write_b128, conflict-free
    }
  };

  loadA(0); loadB(0);
  #pragma unroll
  for (int it = 0; it < 4; ++it) {
    __syncthreads();            // prev-iter LDS reads complete
    storeAB();
    __syncthreads();
    if (it < 3) { loadA((it + 1) * 64); loadB((it + 1) * 64); }  // prefetch next
    #pragma unroll
    for (int kk = 0; kk < 2; kk++) {
      s8 afr[4], bfr[4];
      #pragma unroll
      for (int i = 0; i < 4; i++)
        afr[i] = *(const s8*)(&As[(wm + i * 16 + fr) * LDP + kk * 32 + quad * 8]);
      #pragma unroll
      for (int i = 0; i < 4; i++)
        bfr[i] = *(const s8*)(&Bs[(wn + i * 16 + fr) * LDP + kk * 32 + quad * 8]);
      #pragma unroll
      for (int i = 0; i < 4; i++)
        #pragma unroll
        for (int j = 0; j < 4; j++)
          acc[i][j] = __builtin_amdgcn_mfma_f32_16x16x32_bf16(afr[i], bfr[j], acc[i][j], 0, 0, 0);
    }
  }

  // Epilogue: C/D layout col=lane&15, row=quad*4+reg (verified m89/m91).
  #pragma unroll
  for (int i = 0; i < 4; i++) {
    const int mbase = m0 + wm + i * 16 + quad * 4;
    #pragma unroll
    for (int j = 0; j < 4; j++) {
      const int n = n0 + wn + j * 16 + fr;
      const float bn = bias[n];
      #pragma unroll
      for (int r = 0; r < 4; r++) {
        const size_t m = (size_t)(mbase + r);
        float v = acc[i][j][r] + bn;
        if (RES) v += resid[m * (size_t)N + n];
        if (CBF) ((unsigned short*)Cp)[m * (size_t)N + n] = (unsigned short)f2bf(v);
        else     ((float*)Cp)[m * (size_t)N + n] = v;
      }
    }
  }
}

// Fused v-gemm + p-gemm (independent): grid (625, 3).
//   y=0,1: v = value @ Wv + bv  -> bf16, N=256, quadrant n0=y*128
//   y=2  : p = query @ Wp + bp  -> f32,  N=128
__global__ __launch_bounds__(256)
void fused_vp_k(const float* __restrict__ value, const unsigned short* __restrict__ Wv_t,
                const float* __restrict__ bv, unsigned short* __restrict__ ws_v,
                const float* __restrict__ query, const unsigned short* __restrict__ Wp_t,
                const float* __restrict__ bp, float* __restrict__ ws_p)
{
  __shared__ short As[128 * LDP];
  __shared__ short Bs[128 * LDP];
  const int m0 = blockIdx.x * 128;
  if (blockIdx.y == 2) {
    gemm_body<0, 0, 0>((const void*)query, Wp_t, bp, nullptr, (void*)ws_p,
                       128, m0, 0, As, Bs);
  } else {
    gemm_body<0, 1, 0>((const void*)value, Wv_t, bv, nullptr, (void*)ws_v,
                       256, m0, blockIdx.y * 128, As, Bs);
  }
}

// out = samp @ Wo + bo + query : grid (625, 2), N=256.
__global__ __launch_bounds__(256)
void gemm_out_k(const unsigned short* __restrict__ samp, const unsigned short* __restrict__ Wo_t,
                const float* __restrict__ bo, const float* __restrict__ query,
                float* __restrict__ out)
{
  __shared__ short As[128 * LDP];
  __shared__ short Bs[128 * LDP];
  gemm_body<1, 0, 1>((const void*)samp, Wo_t, bo, query, (void*)out,
                     256, blockIdx.x * 128, blockIdx.y * 128, As, Bs);
}

// ------------------------------------------------------------- sampling ----
// 8 queries per block, 256 threads. Phase A: one (qi,h,pt) per thread ->
// weights/offsets in LDS. Phase B: one (qi,h,dg) per thread; 16 gathers
// issued then sched_barrier(0) pin; dword-pair bf16 unpack FMA. (R6: 54us)
__global__ __launch_bounds__(256, 4)
void sample_k(const unsigned short* __restrict__ v, const float* __restrict__ p,
              const float* __restrict__ ref, unsigned short* __restrict__ o)
{
  const int t  = threadIdx.x;
  const int q0 = blockIdx.x * 8;
  __shared__ float sp[8][128];
  __shared__ float sref[16];
  __shared__ float sw[8][8][4][4];   // [qi][h][pt][corner] weights
  __shared__ int   so[8][8][4][4];   // [qi][h][pt][corner] element offsets
  {
    const float* pb = p + (size_t)q0 * 128;
    float* spf = &sp[0][0];
    *(f4*)(spf + t * 4) = *(const f4*)(pb + t * 4);
    if (t < 16) sref[t] = ref[(size_t)q0 * 2 + t];
  }
  __syncthreads();

  // ---- Phase A: one (qi,h,pt) per thread ----
  {
    const int qa = t >> 5;
    const int ha = (t >> 2) & 7;
    const int pa_ = t & 3;
    const float lg0 = sp[qa][64 + ha * 4 + 0], lg1 = sp[qa][64 + ha * 4 + 1];
    const float lg2 = sp[qa][64 + ha * 4 + 2], lg3 = sp[qa][64 + ha * 4 + 3];
    const float mx = fmaxf(fmaxf(lg0, lg1), fmaxf(lg2, lg3));
    const float e0 = __expf(lg0 - mx), e1 = __expf(lg1 - mx);
    const float e2 = __expf(lg2 - mx), e3 = __expf(lg3 - mx);
    const float inv = 1.f / (e0 + e1 + e2 + e3);
    const float a = ((pa_ == 0) ? e0 : (pa_ == 1) ? e1 : (pa_ == 2) ? e2 : e3) * inv;
    const float rx = sref[qa * 2], ry = sref[qa * 2 + 1];
    const float ox = sp[qa][ha * 8 + pa_ * 2], oy = sp[qa][ha * 8 + pa_ * 2 + 1];
    // px = loc_x*W - 0.5 with loc_x = rx + ox/W  ->  rx*W + ox - 0.5
    const float px = rx * 200.f + ox - 0.5f;
    const float py = ry * 200.f + oy - 0.5f;
    const float x0f = floorf(px), y0f = floorf(py);
    const int ix = (int)x0f, iy = (int)y0f;
    const float fx = px - x0f, fy = py - y0f;
    const float vx0 = (ix >= 0 && ix < GW) ? 1.f : 0.f;
    const float vx1 = (ix + 1 >= 0 && ix + 1 < GW) ? 1.f : 0.f;
    const float vy0 = (iy >= 0 && iy < GH) ? 1.f : 0.f;
    const float vy1 = (iy + 1 >= 0 && iy + 1 < GH) ? 1.f : 0.f;
    f4 wv;
    wv[0] = a * (1.f - fx) * (1.f - fy) * vx0 * vy0;
    wv[1] = a * fx * (1.f - fy) * vx1 * vy0;
    wv[2] = a * (1.f - fx) * fy * vx0 * vy1;
    wv[3] = a * fx * fy * vx1 * vy1;
    const int ix0c = min(max(ix, 0), GW - 1);
    const int ix1c = min(max(ix + 1, 0), GW - 1);
    const int iy0c = min(max(iy, 0), GH - 1);
    const int iy1c = min(max(iy + 1, 0), GH - 1);
    const int r0 = iy0c * (GW * 256);
    const int r1 = iy1c * (GW * 256);
    i4 ov;
    ov[0] = r0 + ix0c * 256;
    ov[1] = r0 + ix1c * 256;
    ov[2] = r1 + ix0c * 256;
    ov[3] = r1 + ix1c * 256;
    *(f4*)&sw[qa][ha][pa_][0] = wv;
    *(i4*)&so[qa][ha][pa_][0] = ov;
  }
  __syncthreads();

  // ---- Phase B: one (qi,h,dg) per thread; gathers pinned in flight ----
  const int qi = t >> 5;
  const int h  = (t >> 2) & 7;
  const int dg = t & 3;
  const int q  = q0 + qi;
  // q0 multiple of 8 -> whole block same batch
  const unsigned short* vb = v + ((q0 >= 40000) ? (size_t)NVPIX * 256 : 0);
  const int cbase = h * 32 + dg * 8;

  i4 ofs[4];
  #pragma unroll
  for (int pt = 0; pt < 4; pt++) ofs[pt] = *(const i4*)&so[qi][h][pt][0];

  u4 g[16];
  #pragma unroll
  for (int pt = 0; pt < 4; pt++)
    #pragma unroll
    for (int c = 0; c < 4; c++)
      g[pt * 4 + c] = *(const u4*)(vb + (unsigned)(ofs[pt][c] + cbase));

  // Pin: nothing below may be scheduled above this point.
  __builtin_amdgcn_sched_barrier(0);

  f4 wts[4];
  #pragma unroll
  for (int pt = 0; pt < 4; pt++) wts[pt] = *(const f4*)&sw[qi][h][pt][0];

  float acc[8];
  #pragma unroll
  for (int e = 0; e < 8; e++) acc[e] = 0.f;

  #pragma unroll
  for (int pt = 0; pt < 4; pt++) {
    #pragma unroll
    for (int c = 0; c < 4; c++) {
      const float wk = wts[pt][c];
      const u4 gu = g[pt * 4 + c];
      #pragma unroll
      for (int d = 0; d < 4; d++) {
        const unsigned u = gu[d];
        acc[2 * d]     += wk * asf(u << 16);           // low bf16
        acc[2 * d + 1] += wk * asf(u & 0xffff0000u);   // high bf16
      }
    }
  }

  s8 res;
  #pragma unroll
  for (int e = 0; e < 8; e++) res[e] = f2bf(acc[e]);
  *(s8*)(o + (size_t)q * 256 + cbase) = res;
}

// --------------------------------------------------------------- launch ----
extern "C" void kernel_launch(void* const* d_in, const int* in_sizes, int n_in,
                              void* d_out, int out_size, void* d_ws, size_t ws_size,
                              hipStream_t stream)
{
  const float* query = (const float*)d_in[0];
  const float* value = (const float*)d_in[1];
  const float* refp  = (const float*)d_in[2];
  // d_in[3] spatial_shapes: compile-time (200,200)
  const float* Wv    = (const float*)d_in[4];
  const float* bv    = (const float*)d_in[5];
  const float* Woff  = (const float*)d_in[6];
  const float* boff  = (const float*)d_in[7];
  const float* Wattn = (const float*)d_in[8];
  const float* battn = (const float*)d_in[9];
  const float* Wo    = (const float*)d_in[10];
  const float* bo    = (const float*)d_in[11];

  char* ws = (char*)d_ws;
  unsigned short* ws_v = (unsigned short*)ws;                  // 80000*256 bf16 = 40.96 MB
  float*          ws_p = (float*)(ws + 40960000);              // 80000*128 f32  = 40.96 MB
  unsigned short* ws_o = (unsigned short*)(ws + 81920000);     // 80000*256 bf16 = 40.96 MB
  unsigned short* Wv_t = (unsigned short*)(ws + 122880000);    // 256*256 bf16
  unsigned short* Wo_t = Wv_t + 65536;                         // 256*256 bf16
  unsigned short* Wp_t = Wo_t + 65536;                         // 128*256 bf16
  float*          bp   = (float*)(Wp_t + 32768);               // 128 f32

  hipLaunchKernelGGL(prep_k, dim3(641), dim3(256), 0, stream,
                     Wv, Wo, Woff, Wattn, boff, battn, Wv_t, Wo_t, Wp_t, bp);
  // fused: v = value@Wv + bv (bf16) and p = query@Wp + bp (f32), one launch
  hipLaunchKernelGGL(fused_vp_k, dim3(625, 3), dim3(256), 0, stream,
                     value, Wv_t, bv, ws_v, query, Wp_t, bp, ws_p);
  // sampling
  hipLaunchKernelGGL(sample_k, dim3(10000), dim3(256), 0, stream,
                     ws_v, ws_p, refp, ws_o);
  // out = samp @ Wo + bo + query -> f32
  hipLaunchKernelGGL(gemm_out_k, dim3(625, 2), dim3(256), 0, stream,
                     ws_o, Wo_t, bo, query, (float*)d_out);
}